// Round 6
// baseline (119.392 us; speedup 1.0000x reference)
//
#include <hip/hip_runtime.h>
#include <hip/hip_bf16.h>

#define NB 64        // buckets over entity-id space
#define BSHIFT 14    // bucket = idx >> 14  (1e6 >> 14 = 61 < 64)
#define LBUF 768     // elements per scatter block

// ---------------------------------------------------------------------------
// K1: global bucket histogram (LDS-aggregated; ~64 int atomics per block).
// ---------------------------------------------------------------------------
__global__ void hist_kernel(const int* __restrict__ a_idx, int na,
                            const int* __restrict__ d_idx, int nd,
                            const int* __restrict__ g_idx, int ng,
                            unsigned* __restrict__ hist)
{
    __shared__ unsigned lh[NB];
    const int ntot = na + nd + ng;
    if (threadIdx.x < NB) lh[threadIdx.x] = 0;
    __syncthreads();
    for (int t = blockIdx.x * blockDim.x + threadIdx.x; t < ntot; t += gridDim.x * blockDim.x) {
        int v;
        if (t < na)           v = a_idx[t];
        else if (t < na + nd) v = d_idx[t - na];
        else                  v = g_idx[t - na - nd];
        atomicAdd(&lh[((unsigned)v >> BSHIFT) & (NB - 1)], 1u);
    }
    __syncthreads();
    if (threadIdx.x < NB && lh[threadIdx.x]) atomicAdd(&hist[threadIdx.x], lh[threadIdx.x]);
}

// ---------------------------------------------------------------------------
// K2: block-local counting-sort scatter. Each block owns elements
// [blk*LBUF, min(+LBUF, ntot)); reserves contiguous spans per bucket via one
// int fetch-add per (block,bucket); writes element ids into order[].
// ---------------------------------------------------------------------------
__global__ void scatter_kernel(const int* __restrict__ a_idx, int na,
                               const int* __restrict__ d_idx, int nd,
                               const int* __restrict__ g_idx, int ng,
                               const unsigned* __restrict__ hist,
                               unsigned* __restrict__ cursor,
                               unsigned* __restrict__ order)
{
    __shared__ unsigned lbuf[LBUF];
    __shared__ unsigned lh[NB], gstart[NB], lcur[NB], hsh[NB];
    const int ntot = na + nd + ng;
    const int r0 = blockIdx.x * LBUF;
    const int r1 = min(r0 + LBUF, ntot);
    if (r0 >= ntot) return;

    if (threadIdx.x < NB) { lh[threadIdx.x] = 0; hsh[threadIdx.x] = hist[threadIdx.x]; }
    __syncthreads();

    for (int t = r0 + (int)threadIdx.x; t < r1; t += blockDim.x) {
        int v;
        if (t < na)           v = a_idx[t];
        else if (t < na + nd) v = d_idx[t - na];
        else                  v = g_idx[t - na - nd];
        const unsigned b = ((unsigned)v >> BSHIFT) & (NB - 1);
        lbuf[t - r0] = b;
        atomicAdd(&lh[b], 1u);
    }
    __syncthreads();

    if (threadIdx.x < NB) {
        unsigned base = 0;
        for (unsigned i = 0; i < threadIdx.x; ++i) base += hsh[i];   // exclusive scan
        gstart[threadIdx.x] = base + atomicAdd(&cursor[threadIdx.x], lh[threadIdx.x]);
        lcur[threadIdx.x] = 0;
    }
    __syncthreads();

    for (int t = r0 + (int)threadIdx.x; t < r1; t += blockDim.x) {
        const unsigned b = lbuf[t - r0];
        const unsigned r = atomicAdd(&lcur[b], 1u);
        order[gstart[b] + r] = (unsigned)t;
    }
}

// ---------------------------------------------------------------------------
// K3: element-parallel dots in bucket-sorted order, 4 elements per 16-lane
// group, fused segment-boundary detection.
// ---------------------------------------------------------------------------
__global__ void dots_kernel(const int* __restrict__ a_idx, const int* __restrict__ a_seg,
                            float* __restrict__ dots_a, int* __restrict__ st_a, int na,
                            const int* __restrict__ d_idx, const int* __restrict__ d_seg,
                            float* __restrict__ dots_d, int* __restrict__ st_d, int nd,
                            const int* __restrict__ g_idx, const int* __restrict__ g_seg,
                            float* __restrict__ dots_g, int* __restrict__ st_g, int ng,
                            const unsigned* __restrict__ order,
                            const int* __restrict__ user_id,
                            const float* __restrict__ ufac,
                            const float* __restrict__ efac,
                            int B)
{
    const int gid = blockIdx.x * blockDim.x + threadIdx.x;
    const int grp = gid >> 4, lane = gid & 15;
    const int ntot = na + nd + ng;
    const int base = 4 * grp;
    if (base >= ntot) return;

    const bool v1 = (base + 1 < ntot), v2 = (base + 2 < ntot), v3 = (base + 3 < ntot);
    const int t0 = (int)order[base];
    const int t1 = v1 ? (int)order[base + 1] : t0;
    const int t2 = v2 ? (int)order[base + 2] : t0;
    const int t3 = v3 ? (int)order[base + 3] : t0;

#define RESOLVE(T, IDX, SEG, DP, ST, EL, NN)                                     \
    if ((T) < na)           { IDX = a_idx; SEG = a_seg; DP = dots_a; ST = st_a; EL = (T);            NN = na; } \
    else if ((T) < na + nd) { IDX = d_idx; SEG = d_seg; DP = dots_d; ST = st_d; EL = (T) - na;       NN = nd; } \
    else                    { IDX = g_idx; SEG = g_seg; DP = dots_g; ST = st_g; EL = (T) - na - nd;  NN = ng; }

    const int *idx0, *seg0; float* dp0; int* st0; int e0, n0;
    const int *idx1, *seg1; float* dp1; int* st1; int e1, n1;
    const int *idx2, *seg2; float* dp2; int* st2; int e2, n2;
    const int *idx3, *seg3; float* dp3; int* st3; int e3, n3;
    RESOLVE(t0, idx0, seg0, dp0, st0, e0, n0);
    RESOLVE(t1, idx1, seg1, dp1, st1, e1, n1);
    RESOLVE(t2, idx2, seg2, dp2, st2, e2, n2);
    RESOLVE(t3, idx3, seg3, dp3, st3, e3, n3);
#undef RESOLVE

    const int s0 = seg0[e0], s1 = seg1[e1], s2 = seg2[e2], s3 = seg3[e3];
    const int i0 = idx0[e0], i1 = idx1[e1], i2 = idx2[e2], i3 = idx3[e3];
    const int u0 = user_id[s0], u1 = user_id[s1], u2 = user_id[s2], u3 = user_id[s3];

    const float4 ev0 = *reinterpret_cast<const float4*>(efac + (size_t)i0 * 64 + lane * 4);
    const float4 ev1 = *reinterpret_cast<const float4*>(efac + (size_t)i1 * 64 + lane * 4);
    const float4 ev2 = *reinterpret_cast<const float4*>(efac + (size_t)i2 * 64 + lane * 4);
    const float4 ev3 = *reinterpret_cast<const float4*>(efac + (size_t)i3 * 64 + lane * 4);
    const float4 uv0 = *reinterpret_cast<const float4*>(ufac + (size_t)u0 * 64 + lane * 4);
    const float4 uv1 = *reinterpret_cast<const float4*>(ufac + (size_t)u1 * 64 + lane * 4);
    const float4 uv2 = *reinterpret_cast<const float4*>(ufac + (size_t)u2 * 64 + lane * 4);
    const float4 uv3 = *reinterpret_cast<const float4*>(ufac + (size_t)u3 * 64 + lane * 4);

    float a0 = uv0.x * ev0.x + uv0.y * ev0.y + uv0.z * ev0.z + uv0.w * ev0.w;
    float a1 = uv1.x * ev1.x + uv1.y * ev1.y + uv1.z * ev1.z + uv1.w * ev1.w;
    float a2 = uv2.x * ev2.x + uv2.y * ev2.y + uv2.z * ev2.z + uv2.w * ev2.w;
    float a3 = uv3.x * ev3.x + uv3.y * ev3.y + uv3.z * ev3.z + uv3.w * ev3.w;

#pragma unroll
    for (int m = 1; m <= 8; m <<= 1) {
        a0 += __shfl_xor(a0, m, 64);
        a1 += __shfl_xor(a1, m, 64);
        a2 += __shfl_xor(a2, m, 64);
        a3 += __shfl_xor(a3, m, 64);
    }

    if (lane == 0)       dp0[e0] = a0;
    if (lane == 1 && v1) dp1[e1] = a1;
    if (lane == 2 && v2) dp2[e2] = a2;
    if (lane == 3 && v3) dp3[e3] = a3;

    if (lane == 4) {
        const int prev = (e0 > 0) ? seg0[e0 - 1] : -1;
        if (prev != s0) st0[s0] = e0;
        if (e0 == n0 - 1) st0[B] = n0;
    }
    if (lane == 5 && v1) {
        const int prev = (e1 > 0) ? seg1[e1 - 1] : -1;
        if (prev != s1) st1[s1] = e1;
        if (e1 == n1 - 1) st1[B] = n1;
    }
    if (lane == 6 && v2) {
        const int prev = (e2 > 0) ? seg2[e2 - 1] : -1;
        if (prev != s2) st2[s2] = e2;
        if (e2 == n2 - 1) st2[B] = n2;
    }
    if (lane == 7 && v3) {
        const int prev = (e3 > 0) ? seg3[e3 - 1] : -1;
        if (prev != s3) st3[s3] = e3;
        if (e3 == n3 - 1) st3[B] = n3;
    }
}

// ---------------------------------------------------------------------------
// K4 (fused segmean + finalize): one 16-lane group per b.
// ---------------------------------------------------------------------------
__global__ void final_kernel(const float* __restrict__ dots_a, const int* __restrict__ st_a,
                             const float* __restrict__ dots_d, const int* __restrict__ st_d,
                             const float* __restrict__ dots_g, const int* __restrict__ st_g,
                             const int* __restrict__ user_id,
                             const float* __restrict__ ufac,
                             const float* __restrict__ relk,   // (64,3) row-major
                             float* __restrict__ out, int B)
{
    const int gid = blockIdx.x * blockDim.x + threadIdx.x;
    const int b = gid >> 4, lane = gid & 15;
    if (b >= B) return;

    const int uid = user_id[b];
    const float4 uv = *reinterpret_cast<const float4*>(ufac + (size_t)uid * 64 + lane * 4);
    const int d0 = lane * 4;
    float s0 = uv.x * relk[(d0 + 0) * 3 + 0] + uv.y * relk[(d0 + 1) * 3 + 0]
             + uv.z * relk[(d0 + 2) * 3 + 0] + uv.w * relk[(d0 + 3) * 3 + 0];
    float s1 = uv.x * relk[(d0 + 0) * 3 + 1] + uv.y * relk[(d0 + 1) * 3 + 1]
             + uv.z * relk[(d0 + 2) * 3 + 1] + uv.w * relk[(d0 + 3) * 3 + 1];
    float s2 = uv.x * relk[(d0 + 0) * 3 + 2] + uv.y * relk[(d0 + 1) * 3 + 2]
             + uv.z * relk[(d0 + 2) * 3 + 2] + uv.w * relk[(d0 + 3) * 3 + 2];

    const int sa = st_a[b], ea = st_a[b + 1];
    const int sd = st_d[b], ed = st_d[b + 1];
    const int sg = st_g[b], eg = st_g[b + 1];
    float ca = 0.f, cd = 0.f, cg = 0.f;
    for (int e = sa + lane; e < ea; e += 16) ca += dots_a[e];
    for (int e = sd + lane; e < ed; e += 16) cd += dots_d[e];
    for (int e = sg + lane; e < eg; e += 16) cg += dots_g[e];

#pragma unroll
    for (int m = 1; m <= 8; m <<= 1) {
        s0 += __shfl_xor(s0, m, 64);
        s1 += __shfl_xor(s1, m, 64);
        s2 += __shfl_xor(s2, m, 64);
        ca += __shfl_xor(ca, m, 64);
        cd += __shfl_xor(cd, m, 64);
        cg += __shfl_xor(cg, m, 64);
    }

    if (lane == 0) {
        ca /= (float)(ea - sa);
        cd /= (float)(ed - sd);
        cg /= (float)(eg - sg);

        s0 = s0 > 0.f ? s0 : 0.2f * s0;
        s1 = s1 > 0.f ? s1 : 0.2f * s1;
        s2 = s2 > 0.f ? s2 : 0.2f * s2;
        const float mx = fmaxf(s0, fmaxf(s1, s2));
        const float x0 = expf(s0 - mx), x1 = expf(s1 - mx), x2 = expf(s2 - mx);
        const float inv = 1.0f / (x0 + x1 + x2);
        const float p0 = x0 * inv, p1 = x1 * inv, p2 = x2 * inv;

        out[b] = (ca * p0 + cd * p1 + cg * p2) / (p0 + p1 + p2);
        out[(size_t)B + 3 * b + 0] = p0;
        out[(size_t)B + 3 * b + 1] = p1;
        out[(size_t)B + 3 * b + 2] = p2;
        out[(size_t)4 * B + b] = ca;
        out[(size_t)5 * B + b] = cd;
        out[(size_t)6 * B + b] = cg;
    }
}

extern "C" void kernel_launch(void* const* d_in, const int* in_sizes, int n_in,
                              void* d_out, int out_size, void* d_ws, size_t ws_size,
                              hipStream_t stream) {
    const int*   user_id = (const int*)  d_in[0];
    const int*   a_idx   = (const int*)  d_in[1];
    const int*   a_seg   = (const int*)  d_in[2];
    const int*   dd_idx  = (const int*)  d_in[3];
    const int*   dd_seg  = (const int*)  d_in[4];
    const int*   g_idx   = (const int*)  d_in[5];
    const int*   g_seg   = (const int*)  d_in[6];
    const float* ufac    = (const float*)d_in[7];
    const float* efac    = (const float*)d_in[8];
    const float* relk    = (const float*)d_in[9];
    float* out = (float*)d_out;

    const int B  = in_sizes[0];
    const int na = in_sizes[1];
    const int nd = in_sizes[3];
    const int ng = in_sizes[5];
    const int ntot = na + nd + ng;

    // ---- workspace layout (16B-aligned regions) ----
    auto align16 = [](size_t x) { return (x + 15) & ~(size_t)15; };
    char* ws = (char*)d_ws;
    size_t off = 0;
    unsigned* hist   = (unsigned*)(ws + off); off += align16(NB * sizeof(unsigned));
    unsigned* cursor = (unsigned*)(ws + off); off += align16(NB * sizeof(unsigned));
    unsigned* order  = (unsigned*)(ws + off); off += align16((size_t)ntot * sizeof(unsigned));
    float* dots_a = (float*)(ws + off); off += align16((size_t)na * sizeof(float));
    float* dots_d = (float*)(ws + off); off += align16((size_t)nd * sizeof(float));
    float* dots_g = (float*)(ws + off); off += align16((size_t)ng * sizeof(float));
    int*   st_a   = (int*)  (ws + off); off += align16((size_t)(B + 1) * sizeof(int));
    int*   st_d   = (int*)  (ws + off); off += align16((size_t)(B + 1) * sizeof(int));
    int*   st_g   = (int*)  (ws + off); off += align16((size_t)(B + 1) * sizeof(int));

    const int threads = 256;

    // zero hist + cursor (they are adjacent at ws start; 16B-aligned blocks)
    hipMemsetAsync(hist, 0, ((char*)order - (char*)hist), stream);

    hist_kernel<<<512, threads, 0, stream>>>(a_idx, na, dd_idx, nd, g_idx, ng, hist);

    const int sc_blocks = (ntot + LBUF - 1) / LBUF;
    scatter_kernel<<<sc_blocks, threads, 0, stream>>>(a_idx, na, dd_idx, nd, g_idx, ng,
                                                      hist, cursor, order);

    const long n_groups = (ntot + 3) / 4;
    const long dots_threads = n_groups * 16;
    dots_kernel<<<(dots_threads + threads - 1) / threads, threads, 0, stream>>>(
        a_idx, a_seg, dots_a, st_a, na,
        dd_idx, dd_seg, dots_d, st_d, nd,
        g_idx, g_seg, dots_g, st_g, ng,
        order, user_id, ufac, efac, B);

    const int fin_threads = B * 16;
    final_kernel<<<(fin_threads + threads - 1) / threads, threads, 0, stream>>>(
        dots_a, st_a, dots_d, st_d, dots_g, st_g, user_id, ufac, relk, out, B);
}

// Round 7
// 46.960 us; speedup vs baseline: 2.5424x; 2.5424x over previous
//
#include <hip/hip_runtime.h>
#include <hip/hip_bf16.h>

// ---------------------------------------------------------------------------
// Phase 1: element-parallel dot products, 4 elements per 16-lane group (ILP),
// with fused segment-boundary detection (st[] side-channel for phase 2).
// Thread space: ceil(ntot/4) groups of 16 lanes over the concatenated
// element space [0, na+nd+ng).
// Structure note (R3/R6 lessons): no atomics (fp32 atomicAdd churned 42 MB of
// writes, 3x slower) and no index sorting (order[] indirection decoalesces
// the seg/idx/dots metadata, 2.5x slower). Element-order processing keeps all
// metadata streams coalesced; the entity gather is the irreducible random part.
// ---------------------------------------------------------------------------
__global__ void dots_kernel(const int* __restrict__ a_idx, const int* __restrict__ a_seg,
                            float* __restrict__ dots_a, int* __restrict__ st_a, int na,
                            const int* __restrict__ d_idx, const int* __restrict__ d_seg,
                            float* __restrict__ dots_d, int* __restrict__ st_d, int nd,
                            const int* __restrict__ g_idx, const int* __restrict__ g_seg,
                            float* __restrict__ dots_g, int* __restrict__ st_g, int ng,
                            const int* __restrict__ user_id,
                            const float* __restrict__ ufac,
                            const float* __restrict__ efac,
                            int B)
{
    const int gid = blockIdx.x * blockDim.x + threadIdx.x;
    const int grp = gid >> 4, lane = gid & 15;
    const int ntot = na + nd + ng;
    const int base = 4 * grp;
    if (base >= ntot) return;

#define RESOLVE(T, IDX, SEG, DP, ST, EL, NN)                                     \
    if ((T) < na)           { IDX = a_idx; SEG = a_seg; DP = dots_a; ST = st_a; EL = (T);            NN = na; } \
    else if ((T) < na + nd) { IDX = d_idx; SEG = d_seg; DP = dots_d; ST = st_d; EL = (T) - na;       NN = nd; } \
    else                    { IDX = g_idx; SEG = g_seg; DP = dots_g; ST = st_g; EL = (T) - na - nd;  NN = ng; }

    const bool v1 = (base + 1 < ntot), v2 = (base + 2 < ntot), v3 = (base + 3 < ntot);

    const int *idx0, *seg0; float* dp0; int* st0; int e0, n0;
    const int *idx1, *seg1; float* dp1; int* st1; int e1, n1;
    const int *idx2, *seg2; float* dp2; int* st2; int e2, n2;
    const int *idx3, *seg3; float* dp3; int* st3; int e3, n3;
    RESOLVE(base, idx0, seg0, dp0, st0, e0, n0);
    RESOLVE(v1 ? base + 1 : base, idx1, seg1, dp1, st1, e1, n1);
    RESOLVE(v2 ? base + 2 : base, idx2, seg2, dp2, st2, e2, n2);
    RESOLVE(v3 ? base + 3 : base, idx3, seg3, dp3, st3, e3, n3);
#undef RESOLVE

    // scalar index loads (broadcast within the subgroup)
    const int s0 = seg0[e0], s1 = seg1[e1], s2 = seg2[e2], s3 = seg3[e3];
    const int i0 = idx0[e0], i1 = idx1[e1], i2 = idx2[e2], i3 = idx3[e3];
    const int u0 = user_id[s0], u1 = user_id[s1], u2 = user_id[s2], u3 = user_id[s3];

    // 8 independent 16B vector loads per thread
    const float4 ev0 = *reinterpret_cast<const float4*>(efac + (size_t)i0 * 64 + lane * 4);
    const float4 ev1 = *reinterpret_cast<const float4*>(efac + (size_t)i1 * 64 + lane * 4);
    const float4 ev2 = *reinterpret_cast<const float4*>(efac + (size_t)i2 * 64 + lane * 4);
    const float4 ev3 = *reinterpret_cast<const float4*>(efac + (size_t)i3 * 64 + lane * 4);
    const float4 uv0 = *reinterpret_cast<const float4*>(ufac + (size_t)u0 * 64 + lane * 4);
    const float4 uv1 = *reinterpret_cast<const float4*>(ufac + (size_t)u1 * 64 + lane * 4);
    const float4 uv2 = *reinterpret_cast<const float4*>(ufac + (size_t)u2 * 64 + lane * 4);
    const float4 uv3 = *reinterpret_cast<const float4*>(ufac + (size_t)u3 * 64 + lane * 4);

    float a0 = uv0.x * ev0.x + uv0.y * ev0.y + uv0.z * ev0.z + uv0.w * ev0.w;
    float a1 = uv1.x * ev1.x + uv1.y * ev1.y + uv1.z * ev1.z + uv1.w * ev1.w;
    float a2 = uv2.x * ev2.x + uv2.y * ev2.y + uv2.z * ev2.z + uv2.w * ev2.w;
    float a3 = uv3.x * ev3.x + uv3.y * ev3.y + uv3.z * ev3.z + uv3.w * ev3.w;

#pragma unroll
    for (int m = 1; m <= 8; m <<= 1) {
        a0 += __shfl_xor(a0, m, 64);
        a1 += __shfl_xor(a1, m, 64);
        a2 += __shfl_xor(a2, m, 64);
        a3 += __shfl_xor(a3, m, 64);
    }

    // dots writes: lanes 0..3 write their element's value (all lanes hold all sums)
    if (lane == 0)       dp0[e0] = a0;
    if (lane == 1 && v1) dp1[e1] = a1;
    if (lane == 2 && v2) dp2[e2] = a2;
    if (lane == 3 && v3) dp3[e3] = a3;

    // boundary detection: lanes 4..7 handle elements 0..3
    if (lane == 4) {
        const int prev = (e0 > 0) ? seg0[e0 - 1] : -1;
        if (prev != s0) st0[s0] = e0;
        if (e0 == n0 - 1) st0[B] = n0;
    }
    if (lane == 5 && v1) {
        const int prev = (e1 > 0) ? seg1[e1 - 1] : -1;
        if (prev != s1) st1[s1] = e1;
        if (e1 == n1 - 1) st1[B] = n1;
    }
    if (lane == 6 && v2) {
        const int prev = (e2 > 0) ? seg2[e2 - 1] : -1;
        if (prev != s2) st2[s2] = e2;
        if (e2 == n2 - 1) st2[B] = n2;
    }
    if (lane == 7 && v3) {
        const int prev = (e3 > 0) ? seg3[e3 - 1] : -1;
        if (prev != s3) st3[s3] = e3;
        if (e3 == n3 - 1) st3[B] = n3;
    }
}

// ---------------------------------------------------------------------------
// Phase 2 (fused segmean + finalize): one 16-lane group per b.
// ---------------------------------------------------------------------------
__global__ void final_kernel(const float* __restrict__ dots_a, const int* __restrict__ st_a,
                             const float* __restrict__ dots_d, const int* __restrict__ st_d,
                             const float* __restrict__ dots_g, const int* __restrict__ st_g,
                             const int* __restrict__ user_id,
                             const float* __restrict__ ufac,
                             const float* __restrict__ relk,   // (64,3) row-major
                             float* __restrict__ out, int B)
{
    const int gid = blockIdx.x * blockDim.x + threadIdx.x;
    const int b = gid >> 4, lane = gid & 15;
    if (b >= B) return;

    // --- u @ K partials (lane covers dims 4*lane .. 4*lane+3) ---
    const int uid = user_id[b];
    const float4 uv = *reinterpret_cast<const float4*>(ufac + (size_t)uid * 64 + lane * 4);
    const int d0 = lane * 4;
    float s0 = uv.x * relk[(d0 + 0) * 3 + 0] + uv.y * relk[(d0 + 1) * 3 + 0]
             + uv.z * relk[(d0 + 2) * 3 + 0] + uv.w * relk[(d0 + 3) * 3 + 0];
    float s1 = uv.x * relk[(d0 + 0) * 3 + 1] + uv.y * relk[(d0 + 1) * 3 + 1]
             + uv.z * relk[(d0 + 2) * 3 + 1] + uv.w * relk[(d0 + 3) * 3 + 1];
    float s2 = uv.x * relk[(d0 + 0) * 3 + 2] + uv.y * relk[(d0 + 1) * 3 + 2]
             + uv.z * relk[(d0 + 2) * 3 + 2] + uv.w * relk[(d0 + 3) * 3 + 2];

    // --- segment sums (lane-strided) ---
    const int sa = st_a[b], ea = st_a[b + 1];
    const int sd = st_d[b], ed = st_d[b + 1];
    const int sg = st_g[b], eg = st_g[b + 1];
    float ca = 0.f, cd = 0.f, cg = 0.f;
    for (int e = sa + lane; e < ea; e += 16) ca += dots_a[e];
    for (int e = sd + lane; e < ed; e += 16) cd += dots_d[e];
    for (int e = sg + lane; e < eg; e += 16) cg += dots_g[e];

#pragma unroll
    for (int m = 1; m <= 8; m <<= 1) {
        s0 += __shfl_xor(s0, m, 64);
        s1 += __shfl_xor(s1, m, 64);
        s2 += __shfl_xor(s2, m, 64);
        ca += __shfl_xor(ca, m, 64);
        cd += __shfl_xor(cd, m, 64);
        cg += __shfl_xor(cg, m, 64);
    }

    if (lane == 0) {
        ca /= (float)(ea - sa);
        cd /= (float)(ed - sd);
        cg /= (float)(eg - sg);

        s0 = s0 > 0.f ? s0 : 0.2f * s0;
        s1 = s1 > 0.f ? s1 : 0.2f * s1;
        s2 = s2 > 0.f ? s2 : 0.2f * s2;
        const float mx = fmaxf(s0, fmaxf(s1, s2));
        const float x0 = expf(s0 - mx), x1 = expf(s1 - mx), x2 = expf(s2 - mx);
        const float inv = 1.0f / (x0 + x1 + x2);
        const float p0 = x0 * inv, p1 = x1 * inv, p2 = x2 * inv;

        out[b] = (ca * p0 + cd * p1 + cg * p2) / (p0 + p1 + p2);
        out[(size_t)B + 3 * b + 0] = p0;
        out[(size_t)B + 3 * b + 1] = p1;
        out[(size_t)B + 3 * b + 2] = p2;
        out[(size_t)4 * B + b] = ca;
        out[(size_t)5 * B + b] = cd;
        out[(size_t)6 * B + b] = cg;
    }
}

extern "C" void kernel_launch(void* const* d_in, const int* in_sizes, int n_in,
                              void* d_out, int out_size, void* d_ws, size_t ws_size,
                              hipStream_t stream) {
    const int*   user_id = (const int*)  d_in[0];
    const int*   a_idx   = (const int*)  d_in[1];
    const int*   a_seg   = (const int*)  d_in[2];
    const int*   dd_idx  = (const int*)  d_in[3];
    const int*   dd_seg  = (const int*)  d_in[4];
    const int*   g_idx   = (const int*)  d_in[5];
    const int*   g_seg   = (const int*)  d_in[6];
    const float* ufac    = (const float*)d_in[7];
    const float* efac    = (const float*)d_in[8];
    const float* relk    = (const float*)d_in[9];
    float* out = (float*)d_out;

    const int B  = in_sizes[0];
    const int na = in_sizes[1];
    const int nd = in_sizes[3];
    const int ng = in_sizes[5];
    const int ntot = na + nd + ng;

    // ---- workspace layout (16B-aligned regions) ----
    auto align16 = [](size_t x) { return (x + 15) & ~(size_t)15; };
    char* ws = (char*)d_ws;
    size_t off = 0;
    float* dots_a = (float*)(ws + off); off += align16((size_t)na * sizeof(float));
    float* dots_d = (float*)(ws + off); off += align16((size_t)nd * sizeof(float));
    float* dots_g = (float*)(ws + off); off += align16((size_t)ng * sizeof(float));
    int*   st_a   = (int*)  (ws + off); off += align16((size_t)(B + 1) * sizeof(int));
    int*   st_d   = (int*)  (ws + off); off += align16((size_t)(B + 1) * sizeof(int));
    int*   st_g   = (int*)  (ws + off); off += align16((size_t)(B + 1) * sizeof(int));

    const int threads = 256;

    const long n_groups = (ntot + 3) / 4;
    const long dots_threads = n_groups * 16;
    dots_kernel<<<(dots_threads + threads - 1) / threads, threads, 0, stream>>>(
        a_idx, a_seg, dots_a, st_a, na,
        dd_idx, dd_seg, dots_d, st_d, nd,
        g_idx, g_seg, dots_g, st_g, ng,
        user_id, ufac, efac, B);

    const int fin_threads = B * 16;
    final_kernel<<<(fin_threads + threads - 1) / threads, threads, 0, stream>>>(
        dots_a, st_a, dots_d, st_d, dots_g, st_g, user_id, ufac, relk, out, B);
}